// Round 5
// baseline (48.578 us; speedup 1.0000x reference)
//
#include <hip/hip_runtime.h>
#include <hip/hip_bf16.h>

typedef __attribute__((ext_vector_type(4))) float f32x4;
typedef __attribute__((ext_vector_type(8))) short bf16x8;
typedef __attribute__((ext_vector_type(4))) short bf16x4;

#define QS_STRIDE 68            // floats/row: 272B, 16B-aligned; s-reads 2-way (free)
#define BT_STRIDE 72            // shorts/f-row: 144B, 16B-aligned; b128 reads conflict-free
#define SLICE_B   (16 * BT_STRIDE)  // shorts per staged slice (16 f-rows x 64 e)

static __device__ __forceinline__ short f2bf(float x) {
    __hip_bfloat16 h = __float2bfloat16(x);   // RNE; pairs into v_cvt_pk_bf16_f32
    return __builtin_bit_cast(short, h);
}

// LDS-ordering barrier WITHOUT vmcnt drain: global prefetch stays in flight
#define FENCE() do {                                         \
    asm volatile("s_waitcnt lgkmcnt(0)" ::: "memory");       \
    __builtin_amdgcn_s_barrier();                            \
    asm volatile("" ::: "memory");                           \
} while (0)

__global__ __launch_bounds__(256, 2) void quad_form_kernel(
    const float* __restrict__ q, const float* __restrict__ kv, float* __restrict__ out)
{
    __shared__ float qs[256 * QS_STRIDE];                       // 69632 B, full-chunk q*0.125
    __shared__ __align__(16) unsigned short Bt[2][2 * SLICE_B]; // 9216 B, 2 bufs x 2 slices

    const int tid = threadIdx.x;

    // f-split: 4 WGs per chunk, each owns f-range [f0, f0+16) and ALL 256 rows.
    // XCD swizzle keeps the 4 siblings on one XCD (they share q + adjacent 64B S segments).
    const int wg = blockIdx.x;            // 0..511
    const int xcd = wg & 7, p = wg >> 3;  // p: 0..63
    const int chunk = xcd * 16 + (p >> 2);
    const int f0 = (p & 3) * 16;

    const float* qch = q   + (size_t)chunk * 16384;
    const float* Sch = kv  + (size_t)chunk * 262144 + f0;
    float*       och = out + (size_t)chunk * 16384 + f0;

    // ---- stage full q chunk (256x64) into LDS fp32, scaled by 1/8 (exact) ----
#pragma unroll
    for (int i = 0; i < 16; ++i) {
        int idx4 = i * 256 + tid;
        int row = idx4 >> 4, col = (idx4 & 15) << 2;
        f32x4 v = *(const f32x4*)(qch + idx4 * 4);
        v *= 0.125f;
        *(f32x4*)&qs[row * QS_STRIDE + col] = v;
    }

    // ---- S staging map: thread -> (f = tid&15, e-quad = tid>>4) ----
    // Loads: 16 segments of 64B per inst (fully utilized); write: one ds_write_b64.
    const int fT = tid & 15;
    const int eg = tid >> 4;                    // e0 = eg*4
    const float* Sptr = Sch + fT + eg * 4 * 64;

    float rA[8], rB[8];                         // 2 slices per buffer

    auto issue = [&](float* r, int d0) {
        const float* pa = Sptr + d0 * 4096;
        const float* pb = pa + 4096;
#pragma unroll
        for (int i = 0; i < 4; ++i) { r[i] = pa[i * 64]; r[4 + i] = pb[i * 64]; }
    };
    auto stage = [&](const float* r, int buf) {
        unsigned short* base = &Bt[buf][fT * BT_STRIDE + eg * 4];
        bf16x4 w0, w1;
#pragma unroll
        for (int j = 0; j < 4; ++j) { w0[j] = f2bf(r[j]); w1[j] = f2bf(r[4 + j]); }
        *(bf16x4*)base = w0;                    // [f][e] transposed layout
        *(bf16x4*)(base + SLICE_B) = w1;
    };

    // ---- MFMA geometry: wave w owns rows [w*64, w*64+64) = 4 M-tiles x 1 N-tile ----
    const int lane = tid & 63;
    const int w = tid >> 6;
    const int ra = lane & 15, kg = lane >> 4;

    f32x4 acc[4] = {};
    const float* qrow[4];
#pragma unroll
    for (int Mt = 0; Mt < 4; ++Mt) qrow[Mt] = qs + (w * 64 + Mt * 16 + ra) * QS_STRIDE;

    // ---- prologue: fill pipeline (Bt[0] <- slices 0,1; rB holds 2,3; rA refills 4,5) ----
    issue(rA, 0); issue(rB, 2);
    stage(rA, 0);
    issue(rA, 4);
    FENCE();

    // ---- hoist loop-invariant e-segments into 64 VGPRs (immune to fence clobber) ----
    f32x4 u[4][2][2];
#pragma unroll
    for (int Mt = 0; Mt < 4; ++Mt)
#pragma unroll
        for (int Ks = 0; Ks < 2; ++Ks) {
            u[Mt][Ks][0] = *(const f32x4*)(qrow[Mt] + Ks * 32 + kg * 8);
            u[Mt][Ks][1] = *(const f32x4*)(qrow[Mt] + Ks * 32 + kg * 8 + 4);
        }

    auto mfma_pair = [&](int buf, int d0) {
#pragma unroll
        for (int sl = 0; sl < 2; ++sl) {
            float s[4];
#pragma unroll
            for (int Mt = 0; Mt < 4; ++Mt) s[Mt] = qrow[Mt][d0 + sl];  // qs is stable
#pragma unroll
            for (int Ks = 0; Ks < 2; ++Ks) {
                bf16x8 b = *(const bf16x8*)&Bt[buf][sl * SLICE_B + ra * BT_STRIDE + Ks * 32 + kg * 8];
#pragma unroll
                for (int Mt = 0; Mt < 4; ++Mt) {
                    bf16x8 a;
#pragma unroll
                    for (int j = 0; j < 4; ++j) {
                        a[j]     = f2bf(s[Mt] * u[Mt][Ks][0][j]);
                        a[j + 4] = f2bf(s[Mt] * u[Mt][Ks][1][j]);
                    }
                    acc[Mt] = __builtin_amdgcn_mfma_f32_16x16x32_bf16(a, b, acc[Mt], 0, 0, 0);
                }
            }
        }
    };

    // ---- K-loop: 32 phases, 2 slices each; reg buffers ping-pong, 2-phase window ----
#pragma unroll 1
    for (int it = 0; it < 16; ++it) {
        const int d = it * 4;
        stage(rB, 1);                           // slices d+2,d+3 -> Bt[1]
        if (d + 6 < 64) issue(rB, d + 6);
        mfma_pair(0, d);                        // slices d,d+1 from Bt[0]
        FENCE();

        if (d + 4 < 64) {
            stage(rA, 0);                       // slices d+4,d+5 -> Bt[0]
            if (d + 8 < 64) issue(rA, d + 8);
        }
        mfma_pair(1, d + 2);                    // slices d+2,d+3 from Bt[1]
        if (it < 15) FENCE();
    }

    // ---- epilogue: out = 0.5 * acc ----
#pragma unroll
    for (int Mt = 0; Mt < 4; ++Mt)
#pragma unroll
        for (int j = 0; j < 4; ++j) {
            int r = w * 64 + Mt * 16 + kg * 4 + j;
            och[r * 64 + ra] = 0.5f * acc[Mt][j];
        }
}

extern "C" void kernel_launch(void* const* d_in, const int* in_sizes, int n_in,
                              void* d_out, int out_size, void* d_ws, size_t ws_size,
                              hipStream_t stream) {
    const float* q  = (const float*)d_in[0];
    const float* kv = (const float*)d_in[1];
    float* out = (float*)d_out;
    hipLaunchKernelGGL(quad_form_kernel, dim3(512), dim3(256), 0, stream, q, kv, out);
}